// Round 4
// baseline (843.365 us; speedup 1.0000x reference)
//
#include <hip/hip_runtime.h>
#include <hip/hip_bf16.h>

#define N_NODES 50000
#define N_EDGES 800000
#define D 128
#define BATCHSIZE 64

// Coarse binning: 128 dst-nodes per bucket
#define CHUNK_BITS 7
#define CHUNK 128
#define NBUCKETS 391          // ceil(50000/128)
#define NBUCKETS_PAD 392
#define CAP 2400              // mean 2048 + ~7.8 sigma
#define BIN_THREADS 256
#define BIN_EPT 8
#define BIN_TILE (BIN_THREADS * BIN_EPT)   // 2048 edges/block

// ---------------- Kernel 1: coarse binning ----------------
// Per block: LDS histogram over buckets, one global atomicAdd per (block,bucket)
// to reserve, then write packed (src<<7 | dstlo) with tile-contiguous runs.
__global__ __launch_bounds__(BIN_THREADS) void bin_kernel(
    const int* __restrict__ edge_index,
    int* __restrict__ gcur,          // [NBUCKETS], pre-zeroed; ends as counts
    int* __restrict__ bucket)        // [NBUCKETS*CAP]
{
    __shared__ int cnt[NBUCKETS_PAD];
    __shared__ int gbase[NBUCKETS_PAD];
    __shared__ int lcur[NBUCKETS_PAD];
    int t = threadIdx.x;
    for (int b = t; b < NBUCKETS_PAD; b += BIN_THREADS) { cnt[b] = 0; lcur[b] = 0; }
    __syncthreads();

    int packs[BIN_EPT];
    int bs[BIN_EPT];
    int e0 = blockIdx.x * BIN_TILE + t;
#pragma unroll
    for (int i = 0; i < BIN_EPT; ++i) {
        int e = e0 + i * BIN_THREADS;
        if (e < N_EDGES) {
            int s = edge_index[e];
            int d = edge_index[N_EDGES + e];
            int b = d >> CHUNK_BITS;
            bs[i] = b;
            packs[i] = (s << CHUNK_BITS) | (d & (CHUNK - 1));
            atomicAdd(&cnt[b], 1);
        } else {
            bs[i] = -1;
        }
    }
    __syncthreads();
    // reserve global ranges: one atomic per non-empty (block,bucket)
    for (int b = t; b < NBUCKETS; b += BIN_THREADS) {
        int c = cnt[b];
        gbase[b] = c ? atomicAdd(&gcur[b], c) : 0;
    }
    __syncthreads();
    // assign local positions and write
#pragma unroll
    for (int i = 0; i < BIN_EPT; ++i) {
        if (bs[i] >= 0) {
            int p = atomicAdd(&lcur[bs[i]], 1);
            int gpos = gbase[bs[i]] + p;
            if (gpos < CAP) bucket[bs[i] * CAP + gpos] = packs[i];
        }
    }
}

// ---------------- Kernel 2: per-chunk LDS aggregation + finalize + fused pool ----
__global__ __launch_bounds__(1024) void gather_chunk_kernel(
    const float* __restrict__ x,
    const float* __restrict__ eps,
    const int* __restrict__ batch,
    const int* __restrict__ gcur,    // bucket counts
    const int* __restrict__ bucket,
    float* __restrict__ out,
    float* __restrict__ S)           // [64][128], pre-zeroed
{
    __shared__ float agg[CHUNK * D];     // 64 KB
    __shared__ int   ebuf[CAP];          // 9.6 KB
    __shared__ float pool[8 * D];        // 4 KB

    int c = blockIdx.x;
    int t = threadIdx.x;
    int lane = t & 31;
    int g = t >> 5;                      // 32 groups of 32 lanes

    for (int i = t; i < CHUNK * D; i += 1024) agg[i] = 0.0f;
    for (int i = t; i < 8 * D; i += 1024) pool[i] = 0.0f;

    int cnt = gcur[c];
    if (cnt > CAP) cnt = CAP;
    for (int i = t; i < cnt; i += 1024) ebuf[i] = bucket[c * CAP + i];
    __syncthreads();

    // edge loop: group g takes idx = g, g+32, ... ; unroll 2 for MLP
    int idx = g;
    for (; idx + 32 < cnt; idx += 64) {
        int p0 = ebuf[idx];
        int p1 = ebuf[idx + 32];
        int s0 = p0 >> CHUNK_BITS, d0 = p0 & (CHUNK - 1);
        int s1 = p1 >> CHUNK_BITS, d1 = p1 & (CHUNK - 1);
        const float4 v0 = *(const float4*)(x + (size_t)s0 * D + lane * 4);
        const float4 v1 = *(const float4*)(x + (size_t)s1 * D + lane * 4);
        float* a0 = &agg[d0 * D + lane * 4];
        atomicAdd(a0 + 0, v0.x); atomicAdd(a0 + 1, v0.y);
        atomicAdd(a0 + 2, v0.z); atomicAdd(a0 + 3, v0.w);
        float* a1 = &agg[d1 * D + lane * 4];
        atomicAdd(a1 + 0, v1.x); atomicAdd(a1 + 1, v1.y);
        atomicAdd(a1 + 2, v1.z); atomicAdd(a1 + 3, v1.w);
    }
    for (; idx < cnt; idx += 32) {
        int p0 = ebuf[idx];
        int s0 = p0 >> CHUNK_BITS, d0 = p0 & (CHUNK - 1);
        const float4 v0 = *(const float4*)(x + (size_t)s0 * D + lane * 4);
        float* a0 = &agg[d0 * D + lane * 4];
        atomicAdd(a0 + 0, v0.x); atomicAdd(a0 + 1, v0.y);
        atomicAdd(a0 + 2, v0.z); atomicAdd(a0 + 3, v0.w);
    }
    __syncthreads();

    // finalize: out = relu((1+eps)x + agg); fused per-batch pooling into LDS
    int node0 = c << CHUNK_BITS;
    int base_b = batch[node0];
    float scale = 1.0f + eps[0];
#pragma unroll
    for (int k = 0; k < CHUNK / 32; ++k) {       // 4 nodes per group
        int dl = g * (CHUNK / 32) + k;
        int node = node0 + dl;
        if (node >= N_NODES) break;
        float4 av = *(float4*)&agg[dl * D + lane * 4];
        const float4 xv = *(const float4*)(x + (size_t)node * D + lane * 4);
        float4 o;
        o.x = fmaxf(fmaf(scale, xv.x, av.x), 0.0f);
        o.y = fmaxf(fmaf(scale, xv.y, av.y), 0.0f);
        o.z = fmaxf(fmaf(scale, xv.z, av.z), 0.0f);
        o.w = fmaxf(fmaf(scale, xv.w, av.w), 0.0f);
        *(float4*)(out + (size_t)node * D + lane * 4) = o;
        int dv = batch[node] - base_b;
        if (dv < 8) {
            float* pp = &pool[dv * D + lane * 4];
            atomicAdd(pp + 0, o.x); atomicAdd(pp + 1, o.y);
            atomicAdd(pp + 2, o.z); atomicAdd(pp + 3, o.w);
        } else {  // safety fallback (not expected for this input)
            float* sp = S + (size_t)(base_b + dv) * D + lane * 4;
            atomicAdd(sp + 0, o.x); atomicAdd(sp + 1, o.y);
            atomicAdd(sp + 2, o.z); atomicAdd(sp + 3, o.w);
        }
    }
    __syncthreads();

    // flush pool buffer to global S (<= used*128 atomics per block)
    int lastnode = node0 + CHUNK - 1;
    if (lastnode >= N_NODES) lastnode = N_NODES - 1;
    int used = batch[lastnode] - base_b + 1;
    if (used > 8) used = 8;
    for (int i = t; i < used * D; i += 1024) {
        int dv = i >> 7;
        int col = i & (D - 1);
        atomicAdd(&S[(size_t)(base_b + dv) * D + col], pool[i]);
    }
}

__device__ inline int lower_bound_dev(const int* __restrict__ a, int n, int key) {
    int lo = 0, hi = n;
    while (lo < hi) {
        int mid = (lo + hi) >> 1;
        if (a[mid] < key) lo = mid + 1; else hi = mid;
    }
    return lo;
}

// ---------------- Kernel 3: pooled2 = S @ W + count_b * b_pred ----------------
__global__ void pool_gemm_kernel(const float* __restrict__ S,
                                 const int* __restrict__ batch,
                                 const float* __restrict__ W,
                                 const float* __restrict__ b_pred,
                                 float* __restrict__ pooled2) {
    int b = blockIdx.x;      // 64
    int j = threadIdx.x;     // 128
    int lo = lower_bound_dev(batch, N_NODES, b);
    int hi = lower_bound_dev(batch, N_NODES, b + 1);
    float acc = (float)(hi - lo) * b_pred[j];
    const float* srow = S + (size_t)b * D;
#pragma unroll 8
    for (int k = 0; k < D; ++k) {
        acc = fmaf(srow[k], W[(size_t)k * D + j], acc);
    }
    pooled2[(size_t)b * D + j] = acc;
}

// ---------------- fallback (round-1) path, tiny ws ----------------

__global__ void edge_scatter_kernel(const float* __restrict__ x,
                                    const int* __restrict__ edge_index,
                                    float* __restrict__ agg) {
    int tid = blockIdx.x * blockDim.x + threadIdx.x;
    int lane = tid & 31;
    int e = tid >> 5;
    if (e >= N_EDGES) return;
    int src = edge_index[e];
    int dst = edge_index[N_EDGES + e];
    const float4 v = *(const float4*)(x + (size_t)src * D + lane * 4);
    float* dp = agg + (size_t)dst * D + lane * 4;
    atomicAdd(dp + 0, v.x);
    atomicAdd(dp + 1, v.y);
    atomicAdd(dp + 2, v.z);
    atomicAdd(dp + 3, v.w);
}

__global__ void finalize_kernel(const float* __restrict__ x,
                                const float* __restrict__ eps,
                                const int* __restrict__ batch,
                                float* __restrict__ out,
                                float* __restrict__ Sf,
                                float* __restrict__ counts) {
    int tid = blockIdx.x * blockDim.x + threadIdx.x;
    int lane = tid & 31;
    int node = tid >> 5;
    if (node >= N_NODES) return;
    float scale = 1.0f + eps[0];
    const float4 xv = *(const float4*)(x + (size_t)node * D + lane * 4);
    float4 av = *(float4*)(out + (size_t)node * D + lane * 4);
    float4 o;
    o.x = fmaxf(fmaf(scale, xv.x, av.x), 0.0f);
    o.y = fmaxf(fmaf(scale, xv.y, av.y), 0.0f);
    o.z = fmaxf(fmaf(scale, xv.z, av.z), 0.0f);
    o.w = fmaxf(fmaf(scale, xv.w, av.w), 0.0f);
    *(float4*)(out + (size_t)node * D + lane * 4) = o;
    int b = batch[node];
    float* sp = Sf + (size_t)b * D + lane * 4;
    atomicAdd(sp + 0, o.x);
    atomicAdd(sp + 1, o.y);
    atomicAdd(sp + 2, o.z);
    atomicAdd(sp + 3, o.w);
    if (lane == 0) atomicAdd(counts + b, 1.0f);
}

__global__ void pool_gemm_fallback_kernel(const float* __restrict__ Sf,
                                          const float* __restrict__ counts,
                                          const float* __restrict__ W,
                                          const float* __restrict__ b_pred,
                                          float* __restrict__ pooled2) {
    int b = blockIdx.x;
    int j = threadIdx.x;
    float acc = counts[b] * b_pred[j];
    const float* srow = Sf + (size_t)b * D;
#pragma unroll 8
    for (int k = 0; k < D; ++k) {
        acc = fmaf(srow[k], W[(size_t)k * D + j], acc);
    }
    pooled2[(size_t)b * D + j] = acc;
}

extern "C" void kernel_launch(void* const* d_in, const int* in_sizes, int n_in,
                              void* d_out, int out_size, void* d_ws, size_t ws_size,
                              hipStream_t stream) {
    const float* x      = (const float*)d_in[0];
    const float* eps    = (const float*)d_in[1];
    const float* W_pred = (const float*)d_in[2];
    const float* b_pred = (const float*)d_in[3];
    const int*   eidx   = (const int*)d_in[4];
    const int*   batch  = (const int*)d_in[5];

    float* out     = (float*)d_out;                       // [N_NODES][D]
    float* pooled2 = (float*)d_out + (size_t)N_NODES * D; // [BATCHSIZE][D]

    // ws layout (4B units): gcur[392] | S[8192] | bucket[NBUCKETS*CAP]
    const size_t need = (size_t)(NBUCKETS_PAD + BATCHSIZE * D + (size_t)NBUCKETS * CAP) * 4;

    if (ws_size >= need) {
        int*   gcur   = (int*)d_ws;
        float* S      = (float*)d_ws + NBUCKETS_PAD;
        int*   bucket = (int*)d_ws + NBUCKETS_PAD + BATCHSIZE * D;

        // zero gcur + S (contiguous, ~34 KB)
        hipMemsetAsync(d_ws, 0, (size_t)(NBUCKETS_PAD + BATCHSIZE * D) * 4, stream);

        int bin_blocks = (N_EDGES + BIN_TILE - 1) / BIN_TILE;   // 391
        bin_kernel<<<bin_blocks, BIN_THREADS, 0, stream>>>(eidx, gcur, bucket);
        gather_chunk_kernel<<<NBUCKETS, 1024, 0, stream>>>(x, eps, batch, gcur, bucket, out, S);
        pool_gemm_kernel<<<BATCHSIZE, D, 0, stream>>>(S, batch, W_pred, b_pred, pooled2);
    } else {
        // fallback: atomic scatter path
        float* S       = (float*)d_ws;
        float* countsf = (float*)d_ws + BATCHSIZE * D;
        hipMemsetAsync(out, 0, (size_t)N_NODES * D * sizeof(float), stream);
        hipMemsetAsync(d_ws, 0, (BATCHSIZE * D + BATCHSIZE) * sizeof(float), stream);
        {
            long long total = (long long)N_EDGES * 32;
            int blocks = (int)((total + 255) / 256);
            edge_scatter_kernel<<<blocks, 256, 0, stream>>>(x, eidx, out);
        }
        {
            long long total = (long long)N_NODES * 32;
            int blocks = (int)((total + 255) / 256);
            finalize_kernel<<<blocks, 256, 0, stream>>>(x, eps, batch, out, S, countsf);
        }
        pool_gemm_fallback_kernel<<<BATCHSIZE, D, 0, stream>>>(S, countsf, W_pred, b_pred, pooled2);
    }
}

// Round 5
// 172.709 us; speedup vs baseline: 4.8832x; 4.8832x over previous
//
#include <hip/hip_runtime.h>
#include <hip/hip_bf16.h>

#define N_NODES 50000
#define N_EDGES 800000
#define D 128
#define BATCHSIZE 64

// Coarse binning: 128 dst-nodes per bucket
#define CHUNK_BITS 7
#define CHUNK 128
#define NBUCKETS 391          // ceil(50000/128)
#define NBUCKETS_PAD 392
#define CAP 2400              // mean 2048 + ~7.8 sigma (proven round 4)
#define BIN_THREADS 256
#define BIN_EPT 8
#define BIN_TILE (BIN_THREADS * BIN_EPT)   // 2048 edges/block

// ---------------- Kernel 1: coarse binning (proven in round 4) ----------------
__global__ __launch_bounds__(BIN_THREADS) void bin_kernel(
    const int* __restrict__ edge_index,
    int* __restrict__ gcur,          // [NBUCKETS], pre-zeroed; ends as counts
    int* __restrict__ bucket)        // [NBUCKETS*CAP]
{
    __shared__ int cnt[NBUCKETS_PAD];
    __shared__ int gbase[NBUCKETS_PAD];
    __shared__ int lcur[NBUCKETS_PAD];
    int t = threadIdx.x;
    for (int b = t; b < NBUCKETS_PAD; b += BIN_THREADS) { cnt[b] = 0; lcur[b] = 0; }
    __syncthreads();

    int packs[BIN_EPT];
    int bs[BIN_EPT];
    int e0 = blockIdx.x * BIN_TILE + t;
#pragma unroll
    for (int i = 0; i < BIN_EPT; ++i) {
        int e = e0 + i * BIN_THREADS;
        if (e < N_EDGES) {
            int s = edge_index[e];
            int d = edge_index[N_EDGES + e];
            int b = d >> CHUNK_BITS;
            bs[i] = b;
            packs[i] = (s << CHUNK_BITS) | (d & (CHUNK - 1));
            atomicAdd(&cnt[b], 1);
        } else {
            bs[i] = -1;
        }
    }
    __syncthreads();
    for (int b = t; b < NBUCKETS; b += BIN_THREADS) {
        int c = cnt[b];
        gbase[b] = c ? atomicAdd(&gcur[b], c) : 0;
    }
    __syncthreads();
#pragma unroll
    for (int i = 0; i < BIN_EPT; ++i) {
        if (bs[i] >= 0) {
            int p = atomicAdd(&lcur[bs[i]], 1);
            int gpos = gbase[bs[i]] + p;
            if (gpos < CAP) bucket[bs[i] * CAP + gpos] = packs[i];
        }
    }
}

// ---------------- Kernel 2: per-bucket counting sort + register gather ----------
// 1024 threads = 32 groups x 32 lanes. Each group owns 4 dst nodes exclusively:
// no LDS atomics in the feature dimension at all.
__global__ __launch_bounds__(1024) void gather_sort_kernel(
    const float* __restrict__ x,
    const float* __restrict__ eps,
    const int* __restrict__ batch,
    const int* __restrict__ gcur,    // bucket counts
    const int* __restrict__ bucket,
    float* __restrict__ out,
    float* __restrict__ S)           // [64][128], pre-zeroed
{
    __shared__ int   ebuf[CAP];        // 9.6 KB
    __shared__ int   sorted[CAP];      // 9.6 KB (src ids, dst-sorted)
    __shared__ int   hist[CHUNK];
    __shared__ int   offs[CHUNK + 1];
    __shared__ int   cursor[CHUNK];
    __shared__ float pool[8 * D];      // 4 KB

    int c = blockIdx.x;
    int t = threadIdx.x;
    int lane = t & 31;
    int g = t >> 5;

    if (t < CHUNK) hist[t] = 0;
    for (int i = t; i < 8 * D; i += 1024) pool[i] = 0.0f;
    int cnt = gcur[c];
    if (cnt > CAP) cnt = CAP;
    __syncthreads();

    for (int i = t; i < cnt; i += 1024) {
        int p = bucket[c * CAP + i];
        ebuf[i] = p;
        atomicAdd(&hist[p & (CHUNK - 1)], 1);
    }
    __syncthreads();

    // exclusive scan of 128 histogram entries by wave 0 (2 elems/thread)
    if (t < 64) {
        int h0 = hist[2 * t], h1 = hist[2 * t + 1];
        int tot = h0 + h1;
        int incl = tot;
#pragma unroll
        for (int o = 1; o < 64; o <<= 1) {
            int y = __shfl_up(incl, o, 64);
            if (t >= o) incl += y;
        }
        int excl = incl - tot;
        offs[2 * t] = excl;     cursor[2 * t] = excl;
        offs[2 * t + 1] = excl + h0; cursor[2 * t + 1] = excl + h0;
        if (t == 63) offs[CHUNK] = incl;
    }
    __syncthreads();

    // scatter src ids into dst-sorted order
    for (int i = t; i < cnt; i += 1024) {
        int p = ebuf[i];
        int pos = atomicAdd(&cursor[p & (CHUNK - 1)], 1);
        sorted[pos] = p >> CHUNK_BITS;
    }
    __syncthreads();

    // register accumulation: group g owns dsts 4g..4g+3
    int node0 = c << CHUNK_BITS;
    int base_b = batch[node0];
    float scale = 1.0f + eps[0];
    int dv_cur = -1;
    float4 ps = make_float4(0.f, 0.f, 0.f, 0.f);

#pragma unroll
    for (int k = 0; k < 4; ++k) {
        int d = 4 * g + k;
        int node = node0 + d;
        if (node >= N_NODES) break;
        int start = offs[d], end = offs[d + 1];
        float4 acc = make_float4(0.f, 0.f, 0.f, 0.f);
        int i = start;
        for (; i + 4 <= end; i += 4) {
            int s0 = sorted[i], s1 = sorted[i + 1];
            int s2 = sorted[i + 2], s3 = sorted[i + 3];
            const float4 v0 = *(const float4*)(x + (size_t)s0 * D + lane * 4);
            const float4 v1 = *(const float4*)(x + (size_t)s1 * D + lane * 4);
            const float4 v2 = *(const float4*)(x + (size_t)s2 * D + lane * 4);
            const float4 v3 = *(const float4*)(x + (size_t)s3 * D + lane * 4);
            acc.x += (v0.x + v1.x) + (v2.x + v3.x);
            acc.y += (v0.y + v1.y) + (v2.y + v3.y);
            acc.z += (v0.z + v1.z) + (v2.z + v3.z);
            acc.w += (v0.w + v1.w) + (v2.w + v3.w);
        }
        for (; i < end; ++i) {
            int s0 = sorted[i];
            const float4 v0 = *(const float4*)(x + (size_t)s0 * D + lane * 4);
            acc.x += v0.x; acc.y += v0.y; acc.z += v0.z; acc.w += v0.w;
        }
        const float4 xv = *(const float4*)(x + (size_t)node * D + lane * 4);
        float4 o;
        o.x = fmaxf(fmaf(scale, xv.x, acc.x), 0.0f);
        o.y = fmaxf(fmaf(scale, xv.y, acc.y), 0.0f);
        o.z = fmaxf(fmaf(scale, xv.z, acc.z), 0.0f);
        o.w = fmaxf(fmaf(scale, xv.w, acc.w), 0.0f);
        *(float4*)(out + (size_t)node * D + lane * 4) = o;

        int dv = batch[node] - base_b;
        if (dv != dv_cur) {
            if (dv_cur >= 0) {
                if (dv_cur < 8) {
                    float* pp = &pool[dv_cur * D + lane * 4];
                    atomicAdd(pp + 0, ps.x); atomicAdd(pp + 1, ps.y);
                    atomicAdd(pp + 2, ps.z); atomicAdd(pp + 3, ps.w);
                } else {
                    float* sp = S + (size_t)(base_b + dv_cur) * D + lane * 4;
                    atomicAdd(sp + 0, ps.x); atomicAdd(sp + 1, ps.y);
                    atomicAdd(sp + 2, ps.z); atomicAdd(sp + 3, ps.w);
                }
            }
            ps = make_float4(0.f, 0.f, 0.f, 0.f);
            dv_cur = dv;
        }
        ps.x += o.x; ps.y += o.y; ps.z += o.z; ps.w += o.w;
    }
    if (dv_cur >= 0) {
        if (dv_cur < 8) {
            float* pp = &pool[dv_cur * D + lane * 4];
            atomicAdd(pp + 0, ps.x); atomicAdd(pp + 1, ps.y);
            atomicAdd(pp + 2, ps.z); atomicAdd(pp + 3, ps.w);
        } else {
            float* sp = S + (size_t)(base_b + dv_cur) * D + lane * 4;
            atomicAdd(sp + 0, ps.x); atomicAdd(sp + 1, ps.y);
            atomicAdd(sp + 2, ps.z); atomicAdd(sp + 3, ps.w);
        }
    }
    __syncthreads();

    // flush pool to global S: S[(base_b)*D + i] since i = dv*128 + col
    int lastnode = node0 + CHUNK - 1;
    if (lastnode >= N_NODES) lastnode = N_NODES - 1;
    int used = batch[lastnode] - base_b + 1;
    if (used > 8) used = 8;
    for (int i = t; i < used * D; i += 1024) {
        atomicAdd(&S[(size_t)base_b * D + i], pool[i]);
    }
}

__device__ inline int lower_bound_dev(const int* __restrict__ a, int n, int key) {
    int lo = 0, hi = n;
    while (lo < hi) {
        int mid = (lo + hi) >> 1;
        if (a[mid] < key) lo = mid + 1; else hi = mid;
    }
    return lo;
}

// ---------------- Kernel 3: pooled2 = S @ W + count_b * b_pred ----------------
__global__ void pool_gemm_kernel(const float* __restrict__ S,
                                 const int* __restrict__ batch,
                                 const float* __restrict__ W,
                                 const float* __restrict__ b_pred,
                                 float* __restrict__ pooled2) {
    int b = blockIdx.x;      // 64
    int j = threadIdx.x;     // 128
    int lo = lower_bound_dev(batch, N_NODES, b);
    int hi = lower_bound_dev(batch, N_NODES, b + 1);
    float acc = (float)(hi - lo) * b_pred[j];
    const float* srow = S + (size_t)b * D;
#pragma unroll 8
    for (int k = 0; k < D; ++k) {
        acc = fmaf(srow[k], W[(size_t)k * D + j], acc);
    }
    pooled2[(size_t)b * D + j] = acc;
}

// ---------------- fallback (round-1) path, tiny ws ----------------

__global__ void edge_scatter_kernel(const float* __restrict__ x,
                                    const int* __restrict__ edge_index,
                                    float* __restrict__ agg) {
    int tid = blockIdx.x * blockDim.x + threadIdx.x;
    int lane = tid & 31;
    int e = tid >> 5;
    if (e >= N_EDGES) return;
    int src = edge_index[e];
    int dst = edge_index[N_EDGES + e];
    const float4 v = *(const float4*)(x + (size_t)src * D + lane * 4);
    float* dp = agg + (size_t)dst * D + lane * 4;
    atomicAdd(dp + 0, v.x);
    atomicAdd(dp + 1, v.y);
    atomicAdd(dp + 2, v.z);
    atomicAdd(dp + 3, v.w);
}

__global__ void finalize_kernel(const float* __restrict__ x,
                                const float* __restrict__ eps,
                                const int* __restrict__ batch,
                                float* __restrict__ out,
                                float* __restrict__ Sf,
                                float* __restrict__ counts) {
    int tid = blockIdx.x * blockDim.x + threadIdx.x;
    int lane = tid & 31;
    int node = tid >> 5;
    if (node >= N_NODES) return;
    float scale = 1.0f + eps[0];
    const float4 xv = *(const float4*)(x + (size_t)node * D + lane * 4);
    float4 av = *(float4*)(out + (size_t)node * D + lane * 4);
    float4 o;
    o.x = fmaxf(fmaf(scale, xv.x, av.x), 0.0f);
    o.y = fmaxf(fmaf(scale, xv.y, av.y), 0.0f);
    o.z = fmaxf(fmaf(scale, xv.z, av.z), 0.0f);
    o.w = fmaxf(fmaf(scale, xv.w, av.w), 0.0f);
    *(float4*)(out + (size_t)node * D + lane * 4) = o;
    int b = batch[node];
    float* sp = Sf + (size_t)b * D + lane * 4;
    atomicAdd(sp + 0, o.x);
    atomicAdd(sp + 1, o.y);
    atomicAdd(sp + 2, o.z);
    atomicAdd(sp + 3, o.w);
    if (lane == 0) atomicAdd(counts + b, 1.0f);
}

__global__ void pool_gemm_fallback_kernel(const float* __restrict__ Sf,
                                          const float* __restrict__ counts,
                                          const float* __restrict__ W,
                                          const float* __restrict__ b_pred,
                                          float* __restrict__ pooled2) {
    int b = blockIdx.x;
    int j = threadIdx.x;
    float acc = counts[b] * b_pred[j];
    const float* srow = Sf + (size_t)b * D;
#pragma unroll 8
    for (int k = 0; k < D; ++k) {
        acc = fmaf(srow[k], W[(size_t)k * D + j], acc);
    }
    pooled2[(size_t)b * D + j] = acc;
}

extern "C" void kernel_launch(void* const* d_in, const int* in_sizes, int n_in,
                              void* d_out, int out_size, void* d_ws, size_t ws_size,
                              hipStream_t stream) {
    const float* x      = (const float*)d_in[0];
    const float* eps    = (const float*)d_in[1];
    const float* W_pred = (const float*)d_in[2];
    const float* b_pred = (const float*)d_in[3];
    const int*   eidx   = (const int*)d_in[4];
    const int*   batch  = (const int*)d_in[5];

    float* out     = (float*)d_out;                       // [N_NODES][D]
    float* pooled2 = (float*)d_out + (size_t)N_NODES * D; // [BATCHSIZE][D]

    // ws layout (4B units): gcur[392] | S[8192] | bucket[NBUCKETS*CAP]
    const size_t need = (size_t)(NBUCKETS_PAD + BATCHSIZE * D + (size_t)NBUCKETS * CAP) * 4;

    if (ws_size >= need) {
        int*   gcur   = (int*)d_ws;
        float* S      = (float*)d_ws + NBUCKETS_PAD;
        int*   bucket = (int*)d_ws + NBUCKETS_PAD + BATCHSIZE * D;

        hipMemsetAsync(d_ws, 0, (size_t)(NBUCKETS_PAD + BATCHSIZE * D) * 4, stream);

        int bin_blocks = (N_EDGES + BIN_TILE - 1) / BIN_TILE;   // 391
        bin_kernel<<<bin_blocks, BIN_THREADS, 0, stream>>>(eidx, gcur, bucket);
        gather_sort_kernel<<<NBUCKETS, 1024, 0, stream>>>(x, eps, batch, gcur, bucket, out, S);
        pool_gemm_kernel<<<BATCHSIZE, D, 0, stream>>>(S, batch, W_pred, b_pred, pooled2);
    } else {
        // fallback: atomic scatter path
        float* Sf      = (float*)d_ws;
        float* countsf = (float*)d_ws + BATCHSIZE * D;
        hipMemsetAsync(out, 0, (size_t)N_NODES * D * sizeof(float), stream);
        hipMemsetAsync(d_ws, 0, (BATCHSIZE * D + BATCHSIZE) * sizeof(float), stream);
        {
            long long total = (long long)N_EDGES * 32;
            int blocks = (int)((total + 255) / 256);
            edge_scatter_kernel<<<blocks, 256, 0, stream>>>(x, eidx, out);
        }
        {
            long long total = (long long)N_NODES * 32;
            int blocks = (int)((total + 255) / 256);
            finalize_kernel<<<blocks, 256, 0, stream>>>(x, eps, batch, out, Sf, countsf);
        }
        pool_gemm_fallback_kernel<<<BATCHSIZE, D, 0, stream>>>(Sf, countsf, W_pred, b_pred, pooled2);
    }
}